// Round 1
// baseline (19778.362 us; speedup 1.0000x reference)
//
#include <hip/hip_runtime.h>
#include <math.h>

// Persistent-kernel greedy transformer decoder for MI355X.
// B=8, D=512, NH=8 (hd=64), H=2048, NL=2, V=32000, L=48 steps.
// One kernel runs the whole autoregressive decode; 256 blocks x 256 threads
// (1 block/CU -> co-resident), custom agent-scope grid barrier between stages.
// Cross-attention (1 memory token) collapses to a precomputed constant vector.

#define NBK 256
#define NTH 256
#define GTOT (NBK * 16)

namespace cfg {
constexpr int D  = 512;
constexpr int HF = 2048;
constexpr int B  = 8;
constexpr int V  = 32000;
constexpr int SM = 64;          // KV cache stride (>= L+1)
constexpr float EPS = 1e-5f;
constexpr float PE_NEG = -0.017988946039015984f;  // -ln(10000)/512

// workspace layout (float offsets); [0..63] reserved for barrier counters
constexpr size_t O_CAV  = 64;
constexpr size_t O_CAC  = O_CAV + 2 * 8 * 512;    // ca_const[l][b][d]
constexpr size_t O_XB   = O_CAC + 2 * 8 * 512;    // layer-input rows x0 per layer
constexpr size_t O_Q    = O_XB + 2 * 8 * 512;     // q rows
constexpr size_t O_ATT  = O_Q + 8 * 512;          // attention output
constexpr size_t O_Y1   = O_ATT + 8 * 512;        // sa out-proj
constexpr size_t O_X2   = O_Y1 + 8 * 512;         // LN2 output (FFN input)
constexpr size_t O_Y2   = O_X2 + 8 * 512;         // FFN output
constexpr size_t O_HFF  = O_Y2 + 8 * 512;         // relu(ff1) 8x2048
constexpr size_t O_CAND = O_HFF + 8 * 2048;       // per-block argmax cand (float2)
constexpr size_t O_KC   = O_CAND + (size_t)NBK * 8 * 2;
constexpr size_t O_VC   = O_KC + (size_t)2 * 8 * SM * 512;
}

// Generic GEMV stage: out[b][r] = dot(xs_row[b], W[r]) + bias[r], K = 512.
// Rows r = grp*NBK + blockIdx.x (+ k*GTOT): each W row streamed once per grid.
template <typename EPI>
__device__ __forceinline__ void gemv512(const float* __restrict__ W,
                                        const float* __restrict__ bias,
                                        int R, const float* xs, EPI&& epi) {
  const int tid = threadIdx.x;
  const int gl  = tid & 15;
  const int grp = tid >> 4;
  for (int r = grp * NBK + blockIdx.x; r < R; r += GTOT) {
    const float4* wr = (const float4*)(W + (size_t)r * cfg::D);
    float acc[8] = {0.f, 0.f, 0.f, 0.f, 0.f, 0.f, 0.f, 0.f};
#pragma unroll
    for (int i = 0; i < 8; ++i) {
      const float4 w = wr[gl + 16 * i];
#pragma unroll
      for (int b = 0; b < 8; ++b) {
        const float4 a = ((const float4*)(xs + b * cfg::D))[gl + 16 * i];
        acc[b] = fmaf(w.x, a.x, acc[b]);
        acc[b] = fmaf(w.y, a.y, acc[b]);
        acc[b] = fmaf(w.z, a.z, acc[b]);
        acc[b] = fmaf(w.w, a.w, acc[b]);
      }
    }
#pragma unroll
    for (int b = 0; b < 8; ++b) {
      float v = acc[b];
      v += __shfl_xor(v, 1);
      v += __shfl_xor(v, 2);
      v += __shfl_xor(v, 4);
      v += __shfl_xor(v, 8);
      acc[b] = v;
    }
    if (gl < 8) {
      float v = acc[gl];
      if (bias) v += bias[r];
      epi(gl, r, v);
    }
  }
}

__launch_bounds__(NTH)
__global__ void decoder_persistent(
    const float* __restrict__ memory, const float* __restrict__ embedding,
    const float* __restrict__ sa_in_w, const float* __restrict__ sa_in_b,
    const float* __restrict__ sa_out_w, const float* __restrict__ sa_out_b,
    const float* __restrict__ ca_in_w, const float* __restrict__ ca_in_b,
    const float* __restrict__ ca_out_w, const float* __restrict__ ca_out_b,
    const float* __restrict__ ff1_w, const float* __restrict__ ff1_b,
    const float* __restrict__ ff2_w, const float* __restrict__ ff2_b,
    const float* __restrict__ ln1_g, const float* __restrict__ ln1_b,
    const float* __restrict__ ln2_g, const float* __restrict__ ln2_b,
    const float* __restrict__ ln3_g, const float* __restrict__ ln3_b,
    const float* __restrict__ out_w, const float* __restrict__ out_b,
    const int* __restrict__ max_len_p,
    float* __restrict__ dout, float* __restrict__ wsf) {
  using namespace cfg;
  __shared__ __align__(16) float xs[8 * 1024];   // 32 KB activation staging
  __shared__ float red[4];
  __shared__ float2 red2[64];
  __shared__ float2 gcand[16 * 8];
  __shared__ int tok_ls[8];

  const int tid = threadIdx.x;
  const int L = max_len_p[0];

  unsigned* cnt_p = (unsigned*)wsf;        // barrier arrival counter
  unsigned* gen_p = (unsigned*)wsf + 32;   // barrier generation (separate line)

  float* cav  = wsf + O_CAV;
  float* cac  = wsf + O_CAC;
  float* xb   = wsf + O_XB;     // xb + l*4096 = layer-l input rows
  float* qb   = wsf + O_Q;
  float* attn = wsf + O_ATT;
  float* y1   = wsf + O_Y1;
  float* x2g  = wsf + O_X2;
  float* y2   = wsf + O_Y2;
  float* hff  = wsf + O_HFF;
  float2* cand = (float2*)(wsf + O_CAND);
  float* kc   = wsf + O_KC;
  float* vc   = wsf + O_VC;
  float* dlog = dout + (size_t)B * L;      // logits after the token block

  // ---- grid barrier (agent scope, relaxed spin + acq/rel fences) ----
  auto gsync = [&]() {
    __syncthreads();
    __builtin_amdgcn_fence(__ATOMIC_RELEASE, "agent");
    if (tid == 0) {
      unsigned g = __hip_atomic_load(gen_p, __ATOMIC_RELAXED, __HIP_MEMORY_SCOPE_AGENT);
      unsigned old = __hip_atomic_fetch_add(cnt_p, 1u, __ATOMIC_ACQ_REL, __HIP_MEMORY_SCOPE_AGENT);
      if (old == NBK - 1) {
        __hip_atomic_store(cnt_p, 0u, __ATOMIC_RELAXED, __HIP_MEMORY_SCOPE_AGENT);
        __hip_atomic_store(gen_p, g + 1u, __ATOMIC_RELEASE, __HIP_MEMORY_SCOPE_AGENT);
      } else {
        while (__hip_atomic_load(gen_p, __ATOMIC_RELAXED, __HIP_MEMORY_SCOPE_AGENT) == g)
          __builtin_amdgcn_s_sleep(4);
      }
    }
    __syncthreads();
    __builtin_amdgcn_fence(__ATOMIC_ACQUIRE, "agent");
  };

  auto block_sum = [&](float v) -> float {
#pragma unroll
    for (int m = 32; m > 0; m >>= 1) v += __shfl_down(v, m);
    if ((tid & 63) == 0) red[tid >> 6] = v;
    __syncthreads();
    const float t = red[0] + red[1] + red[2] + red[3];
    __syncthreads();
    return t;
  };

  // LayerNorm over 8 rows of 512 into a store functor (exact two-pass like ref)
  auto ln_rows = [&](auto&& load, const float* gamma, const float* beta, auto&& store) {
    const int i0 = tid, i1 = tid + 256;
    for (int b = 0; b < 8; ++b) {
      const float a0 = load(b, i0), a1 = load(b, i1);
      const float m = block_sum(a0 + a1) * (1.0f / 512.0f);
      const float d0 = a0 - m, d1 = a1 - m;
      const float var = block_sum(d0 * d0 + d1 * d1) * (1.0f / 512.0f);
      const float inv = 1.0f / sqrtf(var + EPS);
      store(b, i0, d0 * inv * gamma[i0] + beta[i0]);
      store(b, i1, d1 * inv * gamma[i1] + beta[i1]);
    }
    __syncthreads();
  };

  // ================= init: cross-attn constant (once) =================
  {
    const int gtid = blockIdx.x * NTH + tid;
    if (gtid < 2 * 8 * 512) {  // v_mem = mem @ Wv.T + bv
      const int b = gtid & 7, r = (gtid >> 3) & 511, l = gtid >> 12;
      const float4* a4 = (const float4*)(memory + (size_t)b * 512);
      const float4* w4 = (const float4*)(ca_in_w + ((size_t)l * 1536 + 1024 + r) * 512);
      float s = 0.f;
      for (int i = 0; i < 128; ++i) {
        const float4 a = a4[i], w = w4[i];
        s = fmaf(a.x, w.x, s); s = fmaf(a.y, w.y, s);
        s = fmaf(a.z, w.z, s); s = fmaf(a.w, w.w, s);
      }
      cav[((size_t)l * 8 + b) * 512 + r] = s + ca_in_b[l * 1536 + 1024 + r];
    }
  }
  gsync();
  {
    const int gtid = blockIdx.x * NTH + tid;
    if (gtid < 2 * 8 * 512) {  // ca_const = v_mem @ Wout.T + bout
      const int b = gtid & 7, r = (gtid >> 3) & 511, l = gtid >> 12;
      const float4* a4 = (const float4*)(cav + ((size_t)l * 8 + b) * 512);
      const float4* w4 = (const float4*)(ca_out_w + ((size_t)l * 512 + r) * 512);
      float s = 0.f;
      for (int i = 0; i < 128; ++i) {
        const float4 a = a4[i], w = w4[i];
        s = fmaf(a.x, w.x, s); s = fmaf(a.y, w.y, s);
        s = fmaf(a.z, w.z, s); s = fmaf(a.w, w.w, s);
      }
      cac[((size_t)l * 8 + b) * 512 + r] = s + ca_out_b[l * 512 + r];
    }
  }
  gsync();

  // ================= autoregressive decode =================
  for (int t = 0; t < L; ++t) {
    for (int l = 0; l < 2; ++l) {
      // ---------- QKV prep: build layer input rows in xs ----------
      if (l == 0) {
        if (t > 0) {  // finalize previous token: reduce per-block candidates
          if (tid < 64) {
            const int b = tid >> 3, c = tid & 7;
            float bv = -3.4e38f, bi = 0.f;
            for (int j = 0; j < NBK / 8; ++j) {
              const float2 cv = cand[(size_t)(c * (NBK / 8) + j) * 8 + b];
              if (cv.x > bv || (cv.x == bv && cv.y < bi)) { bv = cv.x; bi = cv.y; }
            }
            red2[tid] = make_float2(bv, bi);
          }
          __syncthreads();
          if (tid < 8) {
            float bv = -3.4e38f, bi = 0.f;
            for (int c = 0; c < 8; ++c) {
              const float2 cv = red2[tid * 8 + c];
              if (cv.x > bv || (cv.x == bv && cv.y < bi)) { bv = cv.x; bi = cv.y; }
            }
            tok_ls[tid] = (int)bi;
            if (blockIdx.x == 0) dout[(size_t)tid * L + (t - 1)] = bi;
          }
        } else {
          if (tid < 8) tok_ls[tid] = 1;  // SOS
        }
        __syncthreads();
        for (int j = tid; j < 8 * 512; j += NTH) {  // embed + positional enc
          const int b = j >> 9, d = j & 511;
          const float ang = (float)t * expf((float)(d & ~1) * PE_NEG);
          const float pe = (d & 1) ? cosf(ang) : sinf(ang);
          xs[j] = embedding[(size_t)tok_ls[b] * 512 + d] + pe;
        }
        __syncthreads();
        if (blockIdx.x < 8) {  // persist x0 rows for FF residual
          const int b = blockIdx.x;
          for (int j = tid; j < 512; j += NTH) xb[(size_t)b * 512 + j] = xs[b * 512 + j];
        }
      } else {
        // x = LN3(x2 + y2) of layer 0; also persist as layer-1 input
        ln_rows([&](int b, int i) { return x2g[(size_t)b * 512 + i] + y2[(size_t)b * 512 + i]; },
                ln3_g, ln3_b,
                [&](int b, int i, float v) {
                  xs[b * 512 + i] = v;
                  if (blockIdx.x == b) xb[(size_t)4096 + b * 512 + i] = v;
                });
      }
      // ---------- QKV GEMV ----------
      gemv512(sa_in_w + (size_t)l * 1536 * 512, sa_in_b + l * 1536, 1536, xs,
              [&](int b, int r, float v) {
                if (r < 512) qb[(size_t)b * 512 + r] = v;
                else if (r < 1024) kc[(((size_t)l * 8 + b) * SM + t) * 512 + (r - 512)] = v;
                else vc[(((size_t)l * 8 + b) * SM + t) * 512 + (r - 1024)] = v;
              });
      gsync();

      // ---------- self-attention: 64 (b,h) units on blocks 0..15 ----------
      if (blockIdx.x < 16) {
        const int wid = tid >> 6, lane = tid & 63;
        const int u = blockIdx.x * 4 + wid, b = u >> 3, h = u & 7;
        float* q_l = xs + wid * 256;
        float* p_l = q_l + 64;
        const float* kcb = kc + ((size_t)(l * 8 + b) * SM) * 512 + h * 64;
        const float* vcb = vc + ((size_t)(l * 8 + b) * SM) * 512 + h * 64;
        q_l[lane] = qb[(size_t)b * 512 + h * 64 + lane];
        __syncthreads();
        if (lane <= t) {
          const float4* k4 = (const float4*)(kcb + (size_t)lane * 512);
          const float4* q4 = (const float4*)q_l;
          float s = 0.f;
#pragma unroll
          for (int i = 0; i < 16; ++i) {
            const float4 kk = k4[i], qq = q4[i];
            s = fmaf(kk.x, qq.x, s); s = fmaf(kk.y, qq.y, s);
            s = fmaf(kk.z, qq.z, s); s = fmaf(kk.w, qq.w, s);
          }
          p_l[lane] = s * 0.125f;  // 1/sqrt(64)
        }
        __syncthreads();
        float mx = -3.4e38f;
        for (int k = 0; k <= t; ++k) mx = fmaxf(mx, p_l[k]);
        __syncthreads();
        if (lane <= t) p_l[lane] = expf(p_l[lane] - mx);
        __syncthreads();
        float den = 0.f, o = 0.f;
        for (int k = 0; k <= t; ++k) {
          const float p = p_l[k];
          den += p;
          o = fmaf(p, vcb[(size_t)k * 512 + lane], o);
        }
        attn[(size_t)b * 512 + h * 64 + lane] = o / den;
      }
      gsync();

      // ---------- attention out-proj ----------
      for (int j = tid; j < 4096; j += NTH) xs[j] = attn[j];
      __syncthreads();
      gemv512(sa_out_w + (size_t)l * 512 * 512, sa_out_b + l * 512, 512, xs,
              [&](int b, int r, float v) { y1[(size_t)b * 512 + r] = v; });
      gsync();

      // ---------- FF1 (with fused LN1 + ca_const + LN2) ----------
      ln_rows([&](int b, int i) { return xb[(size_t)l * 4096 + b * 512 + i] + y1[(size_t)b * 512 + i]; },
              ln1_g + l * 512, ln1_b + l * 512,
              [&](int b, int i, float v) { xs[b * 512 + i] = v; });
      ln_rows([&](int b, int i) { return xs[b * 512 + i] + cac[((size_t)l * 8 + b) * 512 + i]; },
              ln2_g + l * 512, ln2_b + l * 512,
              [&](int b, int i, float v) {
                xs[b * 512 + i] = v;
                if (blockIdx.x == b) x2g[(size_t)b * 512 + i] = v;
              });
      gemv512(ff1_w + (size_t)l * HF * 512, ff1_b + l * HF, HF, xs,
              [&](int b, int r, float v) { hff[(size_t)b * HF + r] = fmaxf(v, 0.f); });
      gsync();

      // ---------- FF2 (K=2048, two 1024-wide tiles) ----------
      {
        const int gl = tid & 15, grp = tid >> 4;
        const int r = grp * NBK + blockIdx.x;
        const bool act = (grp < 2);  // 512 rows total
        float acc[8] = {0.f, 0.f, 0.f, 0.f, 0.f, 0.f, 0.f, 0.f};
        for (int tile = 0; tile < 2; ++tile) {
          __syncthreads();
          for (int j = tid; j < 2048; j += NTH) {  // stage hff[:, tile*1024 .. ]
            const int b = j >> 8, c4 = j & 255;
            ((float4*)xs)[j] = ((const float4*)(hff + (size_t)b * HF + tile * 1024))[c4];
          }
          __syncthreads();
          if (act) {
            const float4* wr = (const float4*)(ff2_w + ((size_t)l * 512 + r) * HF + (size_t)tile * 1024);
#pragma unroll
            for (int i = 0; i < 16; ++i) {
              const float4 w = wr[gl + 16 * i];
#pragma unroll
              for (int b2 = 0; b2 < 8; ++b2) {
                const float4 a = ((const float4*)xs)[b2 * 256 + gl + 16 * i];
                acc[b2] = fmaf(w.x, a.x, acc[b2]);
                acc[b2] = fmaf(w.y, a.y, acc[b2]);
                acc[b2] = fmaf(w.z, a.z, acc[b2]);
                acc[b2] = fmaf(w.w, a.w, acc[b2]);
              }
            }
          }
        }
        if (act) {
#pragma unroll
          for (int b2 = 0; b2 < 8; ++b2) {
            float v = acc[b2];
            v += __shfl_xor(v, 1);
            v += __shfl_xor(v, 2);
            v += __shfl_xor(v, 4);
            v += __shfl_xor(v, 8);
            acc[b2] = v;
          }
          if (gl < 8) y2[(size_t)gl * 512 + r] = acc[gl] + ff2_b[l * 512 + r];
        }
      }
      gsync();
    }  // layer loop

    // ---------- logits + per-block argmax candidates ----------
    ln_rows([&](int b, int i) { return x2g[(size_t)b * 512 + i] + y2[(size_t)b * 512 + i]; },
            ln3_g + 512, ln3_b + 512,
            [&](int b, int i, float v) { xs[b * 512 + i] = v; });
    {
      float bestv = -3.4e38f, besti = 0.f;
      gemv512(out_w, out_b, V, xs, [&](int b, int r, float v) {
        dlog[((size_t)b * L + t) * V + r] = v;
        if (v > bestv) { bestv = v; besti = (float)r; }
      });
      const int gl = tid & 15, grp = tid >> 4;
      if (gl < 8) gcand[grp * 8 + gl] = make_float2(bestv, besti);
      __syncthreads();
      if (tid < 8) {
        float bv = -3.4e38f, bi = 0.f;
        for (int g2 = 0; g2 < 16; ++g2) {
          const float2 cv = gcand[g2 * 8 + tid];
          if (cv.x > bv || (cv.x == bv && cv.y < bi)) { bv = cv.x; bi = cv.y; }
        }
        cand[(size_t)blockIdx.x * 8 + tid] = make_float2(bv, bi);
      }
    }
    gsync();
  }  // t loop

  // ---------- final token (step L-1) ----------
  if (blockIdx.x == 0) {
    if (tid < 64) {
      const int b = tid >> 3, c = tid & 7;
      float bv = -3.4e38f, bi = 0.f;
      for (int j = 0; j < NBK / 8; ++j) {
        const float2 cv = cand[(size_t)(c * (NBK / 8) + j) * 8 + b];
        if (cv.x > bv || (cv.x == bv && cv.y < bi)) { bv = cv.x; bi = cv.y; }
      }
      red2[tid] = make_float2(bv, bi);
    }
    __syncthreads();
    if (tid < 8) {
      float bv = -3.4e38f, bi = 0.f;
      for (int c = 0; c < 8; ++c) {
        const float2 cv = red2[tid * 8 + c];
        if (cv.x > bv || (cv.x == bv && cv.y < bi)) { bv = cv.x; bi = cv.y; }
      }
      dout[(size_t)tid * L + (L - 1)] = bi;
    }
  }
}

extern "C" void kernel_launch(void* const* d_in, const int* in_sizes, int n_in,
                              void* d_out, int out_size, void* d_ws, size_t ws_size,
                              hipStream_t stream) {
  (void)in_sizes; (void)n_in; (void)out_size; (void)ws_size;
  // zero barrier counters (ws is poisoned to 0xAA before each timed call)
  hipMemsetAsync(d_ws, 0, 256, stream);

  const float* memory    = (const float*)d_in[0];
  const float* embedding = (const float*)d_in[1];
  const float* sa_in_w   = (const float*)d_in[2];
  const float* sa_in_b   = (const float*)d_in[3];
  const float* sa_out_w  = (const float*)d_in[4];
  const float* sa_out_b  = (const float*)d_in[5];
  const float* ca_in_w   = (const float*)d_in[6];
  const float* ca_in_b   = (const float*)d_in[7];
  const float* ca_out_w  = (const float*)d_in[8];
  const float* ca_out_b  = (const float*)d_in[9];
  const float* ff1_w     = (const float*)d_in[10];
  const float* ff1_b     = (const float*)d_in[11];
  const float* ff2_w     = (const float*)d_in[12];
  const float* ff2_b     = (const float*)d_in[13];
  const float* ln1_g     = (const float*)d_in[14];
  const float* ln1_b     = (const float*)d_in[15];
  const float* ln2_g     = (const float*)d_in[16];
  const float* ln2_b     = (const float*)d_in[17];
  const float* ln3_g     = (const float*)d_in[18];
  const float* ln3_b     = (const float*)d_in[19];
  const float* out_w     = (const float*)d_in[20];
  const float* out_b     = (const float*)d_in[21];
  const int*   max_len   = (const int*)d_in[22];

  hipLaunchKernelGGL(decoder_persistent, dim3(NBK), dim3(NTH), 0, stream,
                     memory, embedding, sa_in_w, sa_in_b, sa_out_w, sa_out_b,
                     ca_in_w, ca_in_b, ca_out_w, ca_out_b, ff1_w, ff1_b,
                     ff2_w, ff2_b, ln1_g, ln1_b, ln2_g, ln2_b, ln3_g, ln3_b,
                     out_w, out_b, max_len, (float*)d_out, (float*)d_ws);
}

// Round 2
// 8468.018 us; speedup vs baseline: 2.3357x; 2.3357x over previous
//
#include <hip/hip_runtime.h>
#include <math.h>

// Persistent-kernel greedy transformer decoder for MI355X (gfx950).
// B=8, D=512, NH=8 (hd=64), H=2048, NL=2, V=32000, L=48 steps.
// 256 blocks x 512 threads (8 waves = 2/SIMD), co-resident 1 block/CU.
// KEY FIX vs round 1: no agent-scope fences (they buffer_inv/buffer_wbl2 the
// whole per-XCD L2 -> 2.3GB refetch). All cross-block data goes through
// relaxed agent-scope atomics (sc0+sc1, coherent at L3, no cache maint.);
// weights stay L2-cached for the whole kernel. Hierarchical relaxed barrier.

#define NBK 256
#define NTH 512
#define NGRP 32
#define GTOT (NBK * NGRP)   // 8192 16-lane groups

namespace cfg {
constexpr int D  = 512;
constexpr int HF = 2048;
constexpr int V  = 32000;
constexpr int SM = 64;          // KV cache stride (>= L+1)
constexpr float EPS = 1e-5f;
constexpr float PE_NEG = -0.017988946039015984f;  // -ln(10000)/512

// workspace float offsets; [0..1023] = barrier flags
constexpr size_t O_CAV  = 1024;
constexpr size_t O_CAC  = O_CAV + 2 * 8 * 512;
constexpr size_t O_Q    = O_CAC + 2 * 8 * 512;
constexpr size_t O_ATT  = O_Q + 8 * 512;
constexpr size_t O_Y1   = O_ATT + 8 * 512;
constexpr size_t O_Y2   = O_Y1 + 8 * 512;
constexpr size_t O_HFF  = O_Y2 + 8 * 512;
constexpr size_t O_CAND = O_HFF + 8 * 2048;
constexpr size_t O_KC   = O_CAND + (size_t)NBK * 8 * 2;
constexpr size_t O_VC   = O_KC + (size_t)2 * 8 * SM * 512;
}

// device-coherent (L2-bypassing) accesses for cross-block communication
__device__ __forceinline__ float ld_dev(const float* p) {
  return __hip_atomic_load(p, __ATOMIC_RELAXED, __HIP_MEMORY_SCOPE_AGENT);
}
__device__ __forceinline__ void st_dev(float* p, float v) {
  __hip_atomic_store(p, v, __ATOMIC_RELAXED, __HIP_MEMORY_SCOPE_AGENT);
}
union F2U { float2 f; unsigned long long u; };
__device__ __forceinline__ float2 ld_dev2(const float2* p) {
  F2U x; x.u = __hip_atomic_load((const unsigned long long*)p, __ATOMIC_RELAXED, __HIP_MEMORY_SCOPE_AGENT);
  return x.f;
}
__device__ __forceinline__ void st_dev2(float2* p, float2 v) {
  F2U x; x.f = v;
  __hip_atomic_store((unsigned long long*)p, x.u, __ATOMIC_RELAXED, __HIP_MEMORY_SCOPE_AGENT);
}

// GEMV stage: out[b][r] = dot(xs_row[b], W[r]) + bias[r], K = 512, 8 batches.
template <typename EPI>
__device__ __forceinline__ void gemv512(const float* __restrict__ W,
                                        const float* __restrict__ bias,
                                        int R, const float* xs, EPI&& epi) {
  const int tid = threadIdx.x;
  const int gl  = tid & 15;
  const int grp = tid >> 4;
  for (int r = grp * NBK + blockIdx.x; r < R; r += GTOT) {
    const float4* wr = (const float4*)(W + (size_t)r * cfg::D);
    float acc[8] = {0.f, 0.f, 0.f, 0.f, 0.f, 0.f, 0.f, 0.f};
#pragma unroll
    for (int i = 0; i < 8; ++i) {
      const float4 w = wr[gl + 16 * i];
#pragma unroll
      for (int b = 0; b < 8; ++b) {
        const float4 a = ((const float4*)(xs + b * cfg::D))[gl + 16 * i];
        acc[b] = fmaf(w.x, a.x, acc[b]);
        acc[b] = fmaf(w.y, a.y, acc[b]);
        acc[b] = fmaf(w.z, a.z, acc[b]);
        acc[b] = fmaf(w.w, a.w, acc[b]);
      }
    }
#pragma unroll
    for (int b = 0; b < 8; ++b) {
      float v = acc[b];
      v += __shfl_xor(v, 1);
      v += __shfl_xor(v, 2);
      v += __shfl_xor(v, 4);
      v += __shfl_xor(v, 8);
      acc[b] = v;
    }
    if (gl < 8) {
      float v = acc[gl];
      if (bias) v += bias[r];
      epi(gl, r, v);
    }
  }
}

__launch_bounds__(NTH)
__global__ void decoder_persistent(
    const float* __restrict__ memory, const float* __restrict__ embedding,
    const float* __restrict__ sa_in_w, const float* __restrict__ sa_in_b,
    const float* __restrict__ sa_out_w, const float* __restrict__ sa_out_b,
    const float* __restrict__ ca_in_w, const float* __restrict__ ca_in_b,
    const float* __restrict__ ca_out_w, const float* __restrict__ ca_out_b,
    const float* __restrict__ ff1_w, const float* __restrict__ ff1_b,
    const float* __restrict__ ff2_w, const float* __restrict__ ff2_b,
    const float* __restrict__ ln1_g, const float* __restrict__ ln1_b,
    const float* __restrict__ ln2_g, const float* __restrict__ ln2_b,
    const float* __restrict__ ln3_g, const float* __restrict__ ln3_b,
    const float* __restrict__ out_w, const float* __restrict__ out_b,
    const int* __restrict__ max_len_p,
    float* __restrict__ dout, float* __restrict__ wsf) {
  using namespace cfg;
  __shared__ __align__(16) float xs[8192];   // 32 KB activation staging
  __shared__ float2 red2[64];
  __shared__ float2 gcand[NGRP * 8];
  __shared__ int tok_ls[8];

  const int tid  = threadIdx.x;
  const int w    = tid >> 6;    // wave id 0..7 == batch row for LN
  const int lane = tid & 63;
  const int col0 = lane * 8;    // cols owned by this lane in LN mapping
  const int L = max_len_p[0];

  unsigned* bcnt = (unsigned*)wsf;           // 16 sub-counters, 128B apart
  unsigned* bmaster = (unsigned*)wsf + 512;
  unsigned* bgen = (unsigned*)wsf + 544;
  unsigned nbar = 0;

  float* cav  = wsf + O_CAV;
  float* cac  = wsf + O_CAC;
  float* qb   = wsf + O_Q;
  float* attn = wsf + O_ATT;
  float* y1   = wsf + O_Y1;
  float* y2   = wsf + O_Y2;
  float* hff  = wsf + O_HFF;
  float2* cand = (float2*)(wsf + O_CAND);
  float* kc   = wsf + O_KC;
  float* vc   = wsf + O_VC;
  float* dlog = dout + (size_t)8 * L;

  float x0r[8];   // current layer input row w (residual for LN1)
  float x2r[8];   // LN2 output row w (residual for LN3)

  // hierarchical relaxed barrier: NO cache maintenance. __syncthreads drains
  // vmcnt(0) per wave, so this block's sc1 write-through stores are globally
  // visible before tid0 arrives at the counter.
  auto gsync = [&]() {
    __syncthreads();
    if (tid == 0) {
      ++nbar;
      const unsigned sg = (unsigned)blockIdx.x & 15u;
      unsigned old = __hip_atomic_fetch_add(&bcnt[sg * 32], 1u,
                                            __ATOMIC_RELAXED, __HIP_MEMORY_SCOPE_AGENT);
      if ((old & 15u) == 15u) {
        unsigned old2 = __hip_atomic_fetch_add(bmaster, 1u,
                                               __ATOMIC_RELAXED, __HIP_MEMORY_SCOPE_AGENT);
        if ((old2 & 15u) == 15u)
          __hip_atomic_store(bgen, nbar, __ATOMIC_RELAXED, __HIP_MEMORY_SCOPE_AGENT);
      }
      while (__hip_atomic_load(bgen, __ATOMIC_RELAXED, __HIP_MEMORY_SCOPE_AGENT) < nbar)
        __builtin_amdgcn_s_sleep(1);
    }
    __syncthreads();
  };

  // wave-local LayerNorm of row w held in v[8] (cols col0..col0+7)
  auto wave_ln = [&](float (&v)[8], const float* g, const float* bta) {
    float s = 0.f, s2 = 0.f;
#pragma unroll
    for (int j = 0; j < 8; ++j) { s += v[j]; s2 = fmaf(v[j], v[j], s2); }
#pragma unroll
    for (int m = 1; m < 64; m <<= 1) { s += __shfl_xor(s, m); s2 += __shfl_xor(s2, m); }
    const float mean = s * (1.f / 512.f);
    const float var  = s2 * (1.f / 512.f) - mean * mean;
    const float inv  = 1.0f / sqrtf(var + EPS);
    const float4 g0 = ((const float4*)(g + col0))[0], g1 = ((const float4*)(g + col0))[1];
    const float4 b0 = ((const float4*)(bta + col0))[0], b1 = ((const float4*)(bta + col0))[1];
    const float gg[8] = {g0.x, g0.y, g0.z, g0.w, g1.x, g1.y, g1.z, g1.w};
    const float bb[8] = {b0.x, b0.y, b0.z, b0.w, b1.x, b1.y, b1.z, b1.w};
#pragma unroll
    for (int j = 0; j < 8; ++j) v[j] = (v[j] - mean) * inv * gg[j] + bb[j];
  };

  // ================= init: cross-attn constant (once) =================
  {
    const int gtid = blockIdx.x * NTH + tid;
    if (gtid < 2 * 8 * 512) {  // v_mem = mem @ Wv.T + bv
      const int b = gtid & 7, r = (gtid >> 3) & 511, l = gtid >> 12;
      const float4* a4 = (const float4*)(memory + (size_t)b * 512);
      const float4* w4 = (const float4*)(ca_in_w + ((size_t)l * 1536 + 1024 + r) * 512);
      float s = 0.f;
      for (int i = 0; i < 128; ++i) {
        const float4 a = a4[i], ww = w4[i];
        s = fmaf(a.x, ww.x, s); s = fmaf(a.y, ww.y, s);
        s = fmaf(a.z, ww.z, s); s = fmaf(a.w, ww.w, s);
      }
      st_dev(&cav[((size_t)l * 8 + b) * 512 + r], s + ca_in_b[l * 1536 + 1024 + r]);
    }
  }
  gsync();
  {
    const int gtid = blockIdx.x * NTH + tid;
    if (gtid < 2 * 8 * 512) {  // ca_const = v_mem @ Wout.T + bout
      const int b = gtid & 7, r = (gtid >> 3) & 511, l = gtid >> 12;
      const float* a = cav + ((size_t)l * 8 + b) * 512;
      const float4* w4 = (const float4*)(ca_out_w + ((size_t)l * 512 + r) * 512);
      float s = 0.f;
      for (int i = 0; i < 128; ++i) {
        const float4 ww = w4[i];
        s = fmaf(ld_dev(a + 4 * i + 0), ww.x, s);
        s = fmaf(ld_dev(a + 4 * i + 1), ww.y, s);
        s = fmaf(ld_dev(a + 4 * i + 2), ww.z, s);
        s = fmaf(ld_dev(a + 4 * i + 3), ww.w, s);
      }
      st_dev(&cac[((size_t)l * 8 + b) * 512 + r], s + ca_out_b[l * 512 + r]);
    }
  }
  gsync();

  // ================= autoregressive decode =================
  for (int t = 0; t < L; ++t) {
    for (int l = 0; l < 2; ++l) {
      // ---------- build layer input rows into xs (+ x0r regs) ----------
      if (l == 0) {
        if (t > 0) {
          if (tid < 64) {
            const int b = tid >> 3, c = tid & 7;
            float bv = -3.4e38f, bi = 0.f;
            for (int j = 0; j < 32; ++j) {
              const float2 cv = ld_dev2(&cand[(size_t)(c * 32 + j) * 8 + b]);
              if (cv.x > bv || (cv.x == bv && cv.y < bi)) { bv = cv.x; bi = cv.y; }
            }
            red2[tid] = make_float2(bv, bi);
          }
          __syncthreads();
          if (tid < 8) {
            float bv = -3.4e38f, bi = 0.f;
            for (int c = 0; c < 8; ++c) {
              const float2 cv = red2[tid * 8 + c];
              if (cv.x > bv || (cv.x == bv && cv.y < bi)) { bv = cv.x; bi = cv.y; }
            }
            tok_ls[tid] = (int)bi;
            if (blockIdx.x == 0) dout[(size_t)tid * L + (t - 1)] = bi;
          }
        } else {
          if (tid < 8) tok_ls[tid] = 1;  // SOS
        }
        __syncthreads();
        const int tok = tok_ls[w];
        const float4* e4 = (const float4*)(embedding + (size_t)tok * 512 + col0);
        const float4 e0 = e4[0], e1 = e4[1];
        float v[8] = {e0.x, e0.y, e0.z, e0.w, e1.x, e1.y, e1.z, e1.w};
#pragma unroll
        for (int j = 0; j < 8; ++j) {
          const int c = col0 + j;
          const float ang = (float)t * expf((float)(c & ~1) * PE_NEG);
          v[j] += (c & 1) ? cosf(ang) : sinf(ang);
          x0r[j] = v[j];
          xs[w * 512 + c] = v[j];
        }
        __syncthreads();
      } else {
        float v[8];
#pragma unroll
        for (int j = 0; j < 8; ++j) v[j] = x2r[j] + ld_dev(y2 + (size_t)w * 512 + col0 + j);
        wave_ln(v, ln3_g, ln3_b);  // layer-0 LN3
#pragma unroll
        for (int j = 0; j < 8; ++j) { x0r[j] = v[j]; xs[w * 512 + col0 + j] = v[j]; }
        __syncthreads();
      }

      // ---------- QKV GEMV ----------
      gemv512(sa_in_w + (size_t)l * 1536 * 512, sa_in_b + l * 1536, 1536, xs,
              [&](int b, int r, float val) {
                if (r < 512) st_dev(&qb[(size_t)b * 512 + r], val);
                else if (r < 1024) st_dev(&kc[(((size_t)l * 8 + b) * SM + t) * 512 + (r - 512)], val);
                else st_dev(&vc[(((size_t)l * 8 + b) * SM + t) * 512 + (r - 1024)], val);
              });
      gsync();

      // ---------- self-attention: block b handles batch b, wave = head ----
      if (blockIdx.x < 8) {
        const int b = blockIdx.x, h = w;
        float* q_l = xs + h * 128;
        float* p_l = q_l + 64;
        const float* kcb = kc + ((size_t)(l * 8 + b) * SM) * 512 + h * 64;
        const float* vcb = vc + ((size_t)(l * 8 + b) * SM) * 512 + h * 64;
        q_l[lane] = ld_dev(qb + (size_t)b * 512 + h * 64 + lane);
        __syncthreads();
        if (lane <= t) {
          float s = 0.f;
          if (lane < t) {  // immutable rows: normal cached loads
            const float4* k4 = (const float4*)(kcb + (size_t)lane * 512);
            const float4* q4 = (const float4*)q_l;
#pragma unroll
            for (int i = 0; i < 16; ++i) {
              const float4 kk = k4[i], qq = q4[i];
              s = fmaf(kk.x, qq.x, s); s = fmaf(kk.y, qq.y, s);
              s = fmaf(kk.z, qq.z, s); s = fmaf(kk.w, qq.w, s);
            }
          } else {         // row t written this stage: coherent loads
            for (int i = 0; i < 64; ++i)
              s = fmaf(ld_dev(kcb + (size_t)lane * 512 + i), q_l[i], s);
          }
          p_l[lane] = s * 0.125f;
        }
        __syncthreads();
        float mx = -3.4e38f;
        for (int k = 0; k <= t; ++k) mx = fmaxf(mx, p_l[k]);
        __syncthreads();
        if (lane <= t) p_l[lane] = expf(p_l[lane] - mx);
        __syncthreads();
        float den = 0.f, o = 0.f;
        for (int k = 0; k <= t; ++k) {
          const float p = p_l[k];
          const float vv = (k < t) ? vcb[(size_t)k * 512 + lane]
                                   : ld_dev(vcb + (size_t)k * 512 + lane);
          den += p;
          o = fmaf(p, vv, o);
        }
        st_dev(&attn[(size_t)b * 512 + h * 64 + lane], o / den);
      }
      gsync();

      // ---------- attention out-proj ----------
      for (int j = tid; j < 4096; j += NTH) xs[j] = ld_dev(attn + j);
      __syncthreads();
      gemv512(sa_out_w + (size_t)l * 512 * 512, sa_out_b + l * 512, 512, xs,
              [&](int b, int r, float val) { st_dev(&y1[(size_t)b * 512 + r], val); });
      gsync();

      // ---------- LN1 + ca_const + LN2 (in regs) then FF1 ----------
      {
        float v[8];
#pragma unroll
        for (int j = 0; j < 8; ++j) v[j] = x0r[j] + ld_dev(y1 + (size_t)w * 512 + col0 + j);
        wave_ln(v, ln1_g + l * 512, ln1_b + l * 512);
#pragma unroll
        for (int j = 0; j < 8; ++j) v[j] += ld_dev(cac + ((size_t)l * 8 + w) * 512 + col0 + j);
        wave_ln(v, ln2_g + l * 512, ln2_b + l * 512);
#pragma unroll
        for (int j = 0; j < 8; ++j) { x2r[j] = v[j]; xs[w * 512 + col0 + j] = v[j]; }
        __syncthreads();
      }
      gemv512(ff1_w + (size_t)l * HF * 512, ff1_b + l * HF, HF, xs,
              [&](int b, int r, float val) {
                st_dev(&hff[(size_t)b * HF + r], fmaxf(val, 0.f));
              });
      gsync();

      // ---------- FF2 (K=2048, two 1024-wide tiles) ----------
      {
        const int gl = tid & 15, grp = tid >> 4;
        const int r = grp * NBK + blockIdx.x;
        const bool act = (grp < 2);  // 512 rows
        float acc[8] = {0.f, 0.f, 0.f, 0.f, 0.f, 0.f, 0.f, 0.f};
        for (int tile = 0; tile < 2; ++tile) {
          __syncthreads();
          for (int j = tid; j < 8192; j += NTH)
            xs[j] = ld_dev(hff + (size_t)(j >> 10) * HF + tile * 1024 + (j & 1023));
          __syncthreads();
          if (act) {
            const float4* wr = (const float4*)(ff2_w + ((size_t)l * 512 + r) * HF + (size_t)tile * 1024);
#pragma unroll
            for (int i = 0; i < 16; ++i) {
              const float4 ww = wr[gl + 16 * i];
#pragma unroll
              for (int b2 = 0; b2 < 8; ++b2) {
                const float4 a = ((const float4*)xs)[b2 * 256 + gl + 16 * i];
                acc[b2] = fmaf(ww.x, a.x, acc[b2]);
                acc[b2] = fmaf(ww.y, a.y, acc[b2]);
                acc[b2] = fmaf(ww.z, a.z, acc[b2]);
                acc[b2] = fmaf(ww.w, a.w, acc[b2]);
              }
            }
          }
        }
        if (act) {
#pragma unroll
          for (int b2 = 0; b2 < 8; ++b2) {
            float v = acc[b2];
            v += __shfl_xor(v, 1);
            v += __shfl_xor(v, 2);
            v += __shfl_xor(v, 4);
            v += __shfl_xor(v, 8);
            acc[b2] = v;
          }
          if (gl < 8) st_dev(&y2[(size_t)gl * 512 + r], acc[gl] + ff2_b[l * 512 + r]);
        }
      }
      gsync();
    }  // layer loop

    // ---------- final LN3 + logits + per-block argmax candidates ----------
    {
      float v[8];
#pragma unroll
      for (int j = 0; j < 8; ++j) v[j] = x2r[j] + ld_dev(y2 + (size_t)w * 512 + col0 + j);
      wave_ln(v, ln3_g + 512, ln3_b + 512);
#pragma unroll
      for (int j = 0; j < 8; ++j) xs[w * 512 + col0 + j] = v[j];
      __syncthreads();
    }
    {
      float bestv = -3.4e38f, besti = 0.f;
      gemv512(out_w, out_b, V, xs, [&](int b, int r, float val) {
        dlog[((size_t)b * L + t) * V + r] = val;  // normal store; host-read only
        if (val > bestv) { bestv = val; besti = (float)r; }
      });
      const int gl = tid & 15, grp = tid >> 4;
      if (gl < 8) gcand[grp * 8 + gl] = make_float2(bestv, besti);
      __syncthreads();
      if (tid < 8) {
        float bv = -3.4e38f, bi = 0.f;
        for (int g2 = 0; g2 < NGRP; ++g2) {
          const float2 cv = gcand[g2 * 8 + tid];
          if (cv.x > bv || (cv.x == bv && cv.y < bi)) { bv = cv.x; bi = cv.y; }
        }
        st_dev2(&cand[(size_t)blockIdx.x * 8 + tid], make_float2(bv, bi));
      }
    }
    gsync();
  }  // t loop

  // ---------- final token (step L-1) ----------
  if (blockIdx.x == 0) {
    if (tid < 64) {
      const int b = tid >> 3, c = tid & 7;
      float bv = -3.4e38f, bi = 0.f;
      for (int j = 0; j < 32; ++j) {
        const float2 cv = ld_dev2(&cand[(size_t)(c * 32 + j) * 8 + b]);
        if (cv.x > bv || (cv.x == bv && cv.y < bi)) { bv = cv.x; bi = cv.y; }
      }
      red2[tid] = make_float2(bv, bi);
    }
    __syncthreads();
    if (tid < 8) {
      float bv = -3.4e38f, bi = 0.f;
      for (int c = 0; c < 8; ++c) {
        const float2 cv = red2[tid * 8 + c];
        if (cv.x > bv || (cv.x == bv && cv.y < bi)) { bv = cv.x; bi = cv.y; }
      }
      dout[(size_t)tid * L + (L - 1)] = bi;
    }
  }
}

extern "C" void kernel_launch(void* const* d_in, const int* in_sizes, int n_in,
                              void* d_out, int out_size, void* d_ws, size_t ws_size,
                              hipStream_t stream) {
  (void)in_sizes; (void)n_in; (void)out_size; (void)ws_size;
  hipMemsetAsync(d_ws, 0, 4096, stream);  // barrier flags

  const float* memory    = (const float*)d_in[0];
  const float* embedding = (const float*)d_in[1];
  const float* sa_in_w   = (const float*)d_in[2];
  const float* sa_in_b   = (const float*)d_in[3];
  const float* sa_out_w  = (const float*)d_in[4];
  const float* sa_out_b  = (const float*)d_in[5];
  const float* ca_in_w   = (const float*)d_in[6];
  const float* ca_in_b   = (const float*)d_in[7];
  const float* ca_out_w  = (const float*)d_in[8];
  const float* ca_out_b  = (const float*)d_in[9];
  const float* ff1_w     = (const float*)d_in[10];
  const float* ff1_b     = (const float*)d_in[11];
  const float* ff2_w     = (const float*)d_in[12];
  const float* ff2_b     = (const float*)d_in[13];
  const float* ln1_g     = (const float*)d_in[14];
  const float* ln1_b     = (const float*)d_in[15];
  const float* ln2_g     = (const float*)d_in[16];
  const float* ln2_b     = (const float*)d_in[17];
  const float* ln3_g     = (const float*)d_in[18];
  const float* ln3_b     = (const float*)d_in[19];
  const float* out_w     = (const float*)d_in[20];
  const float* out_b     = (const float*)d_in[21];
  const int*   max_len   = (const int*)d_in[22];

  hipLaunchKernelGGL(decoder_persistent, dim3(NBK), dim3(NTH), 0, stream,
                     memory, embedding, sa_in_w, sa_in_b, sa_out_w, sa_out_b,
                     ca_in_w, ca_in_b, ca_out_w, ca_out_b, ff1_w, ff1_b,
                     ff2_w, ff2_b, ln1_g, ln1_b, ln2_g, ln2_b, ln3_g, ln3_b,
                     out_w, out_b, max_len, (float*)d_out, (float*)d_ws);
}